// Round 1
// baseline (437.671 us; speedup 1.0000x reference)
//
#include <hip/hip_runtime.h>

// Fused single-head attention: q,k,v = x@W{q,k,v}+b; softmax(q k^T/32) v
// B=8, S=2048, d_model=dk=dv=1024. Inputs fp32; compute in bf16 MFMA.
//
// ws layout (u16 units):
//   [Wt: 3x1024x1024] [Q: 16384x1024] [K: 16384x1024] [Vt: 8x1024x2048]
//   [SC: 8x2048x2048]  (SC region doubles as xb (first half) and Vtmp
//                       (second half) during the projection phase)
// total = 174,063,616 bytes.

#define DEV __device__ __forceinline__

typedef unsigned short u16;
typedef __attribute__((ext_vector_type(8))) short bf16x8;
typedef __attribute__((ext_vector_type(4))) float f32x4;

DEV float bf2f(u16 u) {
  unsigned v = ((unsigned)u) << 16;
  float f;
  __builtin_memcpy(&f, &v, 4);
  return f;
}
DEV u16 f2bf(float f) {
  unsigned v;
  __builtin_memcpy(&v, &f, 4);
  return (u16)((v + 0x7fffu + ((v >> 16) & 1u)) >> 16);
}

DEV void gload16(const u16* g, u16* l) {
  __builtin_amdgcn_global_load_lds(
      (const __attribute__((address_space(1))) void*)g,
      (__attribute__((address_space(3))) void*)l, 16, 0, 0);
}

// ---------------------------------------------------------------- converts
__global__ __launch_bounds__(256) void cvt_f32_bf16(const float* __restrict__ x,
                                                    u16* __restrict__ y) {
  const long long i = ((long long)blockIdx.x * 256 + threadIdx.x) * 4;
  float4 v = *(const float4*)&x[i];
  ushort4 o;
  o.x = f2bf(v.x); o.y = f2bf(v.y); o.z = f2bf(v.z); o.w = f2bf(v.w);
  *(ushort4*)&y[i] = o;
}

// W [1024][1024] fp32 row-major -> Wt [n][k] bf16 (Wt[n][k] = W[k][n])
__global__ __launch_bounds__(256) void transpose_cvt(const float* __restrict__ W,
                                                     u16* __restrict__ Wt) {
  __shared__ float tl[64][65];
  const int n0 = blockIdx.x * 64;
  const int k0 = blockIdx.y * 64;
  const int tid = threadIdx.x;
  const int c = tid & 31, r = tid >> 5;  // 32 col-pairs x 8 rows
#pragma unroll
  for (int i = 0; i < 8; ++i) {
    const int k = i * 8 + r;
    float2 v2 = *(const float2*)&W[(long long)(k0 + k) * 1024 + n0 + c * 2];
    tl[k][c * 2] = v2.x;
    tl[k][c * 2 + 1] = v2.y;
  }
  __syncthreads();
#pragma unroll
  for (int i = 0; i < 8; ++i) {
    const int n = i * 8 + r;
    ushort2 o;
    o.x = f2bf(tl[c * 2][n]);
    o.y = f2bf(tl[c * 2 + 1][n]);
    *(ushort2*)&Wt[(long long)(n0 + n) * 1024 + k0 + c * 2] = o;
  }
}

// V [b][s][d] bf16 -> Vt [b][d][s] bf16
__global__ __launch_bounds__(256) void transpose_v(const u16* __restrict__ V,
                                                   u16* __restrict__ Vt) {
  __shared__ u16 tl[64][66];
  const int b = blockIdx.z;
  const int d0 = blockIdx.x * 64;
  const int s0 = blockIdx.y * 64;
  const u16* Vb = V + (long long)b * 2048 * 1024;
  u16* Vtb = Vt + (long long)b * 1024 * 2048;
  const int tid = threadIdx.x;
  const int c = tid & 31, r = tid >> 5;
#pragma unroll
  for (int i = 0; i < 8; ++i) {
    const int s = i * 8 + r;
    ushort2 v2 = *(const ushort2*)&Vb[(long long)(s0 + s) * 1024 + d0 + c * 2];
    tl[s][c * 2] = v2.x;
    tl[s][c * 2 + 1] = v2.y;
  }
  __syncthreads();
#pragma unroll
  for (int i = 0; i < 8; ++i) {
    const int d = i * 8 + r;
    ushort2 o;
    o.x = tl[c * 2][d];
    o.y = tl[c * 2 + 1][d];
    *(ushort2*)&Vtb[(long long)(d0 + d) * 2048 + s0 + c * 2] = o;
  }
}

// ---------------------------------------------------------------- GEMM (NT)
// C[m][n] = sum_k A[m][k] * B[n][k]  (both bf16 row-major, K-contiguous)
// OUT_MODE: 0 = bf16 out + bias[n]; 1 = bf16 out * scale; 2 = fp32 out
#define BM 128
#define BN 128
#define BK 32

template <int OUT_MODE>
__global__ __launch_bounds__(256) void gemm_nt(
    const u16* __restrict__ A, const u16* __restrict__ B,
    const float* __restrict__ bias, void* __restrict__ Cv, int M, int N, int K,
    int lda, int ldb, int ldc, long long bA, long long bB, long long bC,
    float scale) {
  __shared__ u16 Asm[2][BM * BK];
  __shared__ u16 Bsm[2][BM * BK];
  const int tid = threadIdx.x;
  const int w = tid >> 6, l = tid & 63;
  const int wr = w >> 1, wc = w & 1;  // 2x2 waves, 64x64 out each
  const int z = blockIdx.z;
  A += (long long)z * bA;
  B += (long long)z * bB;
  const long long tm = (long long)blockIdx.y * BM;
  const long long tn = (long long)blockIdx.x * BN;

  const int srow = l >> 2;       // staging: row within 16-row chunk
  const int scol = (l & 3) * 8;  // staging: k offset (8 bf16 = 16B)

  f32x4 acc[4][4];
  const f32x4 zero = {0.f, 0.f, 0.f, 0.f};
#pragma unroll
  for (int i = 0; i < 4; ++i)
#pragma unroll
    for (int j = 0; j < 4; ++j) acc[i][j] = zero;

  const int nt = K / BK;
  // prologue: stage tile 0 into buf 0
#pragma unroll
  for (int i = 0; i < 2; ++i) {
    const int ch = w * 2 + i;  // 8 chunks of 16 rows x 32 k
    gload16(A + (tm + ch * 16 + srow) * lda + scol, &Asm[0][ch * 512]);
    gload16(B + (tn + ch * 16 + srow) * ldb + scol, &Bsm[0][ch * 512]);
  }

  const int ro = l & 15;        // fragment row/col within 16
  const int ko = (l >> 4) * 8;  // fragment k offset

  for (int t = 0; t < nt; ++t) {
    const int cur = t & 1;
    if (t + 1 < nt) {
      const int k0 = (t + 1) * BK;
#pragma unroll
      for (int i = 0; i < 2; ++i) {
        const int ch = w * 2 + i;
        gload16(A + (tm + ch * 16 + srow) * lda + k0 + scol,
                &Asm[cur ^ 1][ch * 512]);
        gload16(B + (tn + ch * 16 + srow) * ldb + k0 + scol,
                &Bsm[cur ^ 1][ch * 512]);
      }
    }
    __syncthreads();  // drains vmcnt -> buf[cur] ready for all waves
    bf16x8 af[4], bfr[4];
#pragma unroll
    for (int mi = 0; mi < 4; ++mi)
      af[mi] = *(const bf16x8*)&Asm[cur][(wr * 64 + mi * 16 + ro) * BK + ko];
#pragma unroll
    for (int ni = 0; ni < 4; ++ni)
      bfr[ni] = *(const bf16x8*)&Bsm[cur][(wc * 64 + ni * 16 + ro) * BK + ko];
#pragma unroll
    for (int mi = 0; mi < 4; ++mi)
#pragma unroll
      for (int ni = 0; ni < 4; ++ni)
        acc[mi][ni] = __builtin_amdgcn_mfma_f32_16x16x32_bf16(
            af[mi], bfr[ni], acc[mi][ni], 0, 0, 0);
    __syncthreads();  // all reads done before next stage overwrites
  }

  // epilogue: C/D layout col = lane&15, row = (lane>>4)*4 + reg  [m89]
  const int ro4 = (l >> 4) * 4;
  const int co = l & 15;
  if (OUT_MODE == 2) {
    float* C = (float*)Cv + (long long)z * bC;
#pragma unroll
    for (int mi = 0; mi < 4; ++mi) {
      const long long row0 = tm + wr * 64 + mi * 16 + ro4;
#pragma unroll
      for (int ni = 0; ni < 4; ++ni) {
        const long long col = tn + wc * 64 + ni * 16 + co;
#pragma unroll
        for (int r = 0; r < 4; ++r) C[(row0 + r) * ldc + col] = acc[mi][ni][r];
      }
    }
  } else {
    u16* C = (u16*)Cv + (long long)z * bC;
#pragma unroll
    for (int mi = 0; mi < 4; ++mi) {
      const long long row0 = tm + wr * 64 + mi * 16 + ro4;
#pragma unroll
      for (int ni = 0; ni < 4; ++ni) {
        const long long col = tn + wc * 64 + ni * 16 + co;
        const float badd = (OUT_MODE == 0) ? bias[col] : 0.f;
#pragma unroll
        for (int r = 0; r < 4; ++r) {
          float v = acc[mi][ni][r];
          v = (OUT_MODE == 0) ? (v + badd) : v * scale;
          C[(row0 + r) * ldc + col] = f2bf(v);
        }
      }
    }
  }
}

// ---------------------------------------------------------------- softmax
// one block per row of 2048 bf16, in place
__global__ __launch_bounds__(256) void softmax_rows(u16* __restrict__ S) {
  const long long row = blockIdx.x;
  u16* p = S + row * 2048;
  const int tid = threadIdx.x;
  const int w = tid >> 6, l = tid & 63;
  __shared__ float red[8];
  bf16x8 v = *(const bf16x8*)&p[tid * 8];
  float f[8];
#pragma unroll
  for (int j = 0; j < 8; ++j) f[j] = bf2f((u16)v[j]);
  float m = f[0];
#pragma unroll
  for (int j = 1; j < 8; ++j) m = fmaxf(m, f[j]);
#pragma unroll
  for (int off = 32; off > 0; off >>= 1) m = fmaxf(m, __shfl_xor(m, off, 64));
  if (l == 0) red[w] = m;
  __syncthreads();
  m = fmaxf(fmaxf(red[0], red[1]), fmaxf(red[2], red[3]));
  float s = 0.f;
#pragma unroll
  for (int j = 0; j < 8; ++j) {
    f[j] = __expf(f[j] - m);
    s += f[j];
  }
#pragma unroll
  for (int off = 32; off > 0; off >>= 1) s += __shfl_xor(s, off, 64);
  if (l == 0) red[4 + w] = s;
  __syncthreads();
  const float inv = 1.f / (red[4] + red[5] + red[6] + red[7]);
#pragma unroll
  for (int j = 0; j < 8; ++j) v[j] = (short)f2bf(f[j] * inv);
  *(bf16x8*)&p[tid * 8] = v;
}

// ---------------------------------------------------------------- launch
extern "C" void kernel_launch(void* const* d_in, const int* in_sizes, int n_in,
                              void* d_out, int out_size, void* d_ws,
                              size_t ws_size, hipStream_t stream) {
  const float* x = (const float*)d_in[0];
  const float* Wq = (const float*)d_in[1];
  const float* bq = (const float*)d_in[2];
  const float* Wk = (const float*)d_in[3];
  const float* bk = (const float*)d_in[4];
  const float* Wv = (const float*)d_in[5];
  const float* bv = (const float*)d_in[6];
  float* out = (float*)d_out;

  const long long MT = 16384LL;  // B*S
  const long long D = 1024LL;

  u16* ws = (u16*)d_ws;
  u16* Wt = ws;                      // 3 x 1048576
  u16* Q = Wt + 3 * 1048576LL;       // 16777216
  u16* Kb = Q + MT * D;              // 16777216
  u16* Vt = Kb + MT * D;             // 16777216  [b][d][s]
  u16* SC = Vt + MT * D;             // 33554432  [b][q][s]
  u16* xb = SC;                      // overlap: x bf16 (proj phase only)
  u16* Vtmp = SC + MT * D;           // overlap: V pre-transpose

  // 1. convert x to bf16
  cvt_f32_bf16<<<dim3(16384), dim3(256), 0, stream>>>(x, xb);
  // 2. transpose+convert weights
  transpose_cvt<<<dim3(16, 16), dim3(256), 0, stream>>>(Wq, Wt);
  transpose_cvt<<<dim3(16, 16), dim3(256), 0, stream>>>(Wk, Wt + 1048576LL);
  transpose_cvt<<<dim3(16, 16), dim3(256), 0, stream>>>(Wv, Wt + 2097152LL);
  // 3-5. projections: [16384,1024] = xb @ Wt^T + b
  gemm_nt<0><<<dim3(8, 128, 1), dim3(256), 0, stream>>>(
      xb, Wt, bq, Q, 16384, 1024, 1024, 1024, 1024, 1024, 0, 0, 0, 0.f);
  gemm_nt<0><<<dim3(8, 128, 1), dim3(256), 0, stream>>>(
      xb, Wt + 1048576LL, bk, Kb, 16384, 1024, 1024, 1024, 1024, 1024, 0, 0, 0,
      0.f);
  gemm_nt<0><<<dim3(8, 128, 1), dim3(256), 0, stream>>>(
      xb, Wt + 2097152LL, bv, Vtmp, 16384, 1024, 1024, 1024, 1024, 1024, 0, 0,
      0, 0.f);
  // 6. V -> V^T per batch
  transpose_v<<<dim3(16, 32, 8), dim3(256), 0, stream>>>(Vtmp, Vt);
  // 7. scores = Q K^T / 32  (overwrites xb/Vtmp region; they are consumed)
  gemm_nt<1><<<dim3(16, 16, 8), dim3(256), 0, stream>>>(
      Q, Kb, nullptr, SC, 2048, 2048, 1024, 1024, 1024, 2048, 2048 * 1024LL,
      2048 * 1024LL, 2048LL * 2048LL, 0.03125f);
  // 8. softmax rows, in place
  softmax_rows<<<dim3(16384), dim3(256), 0, stream>>>(SC);
  // 9. out = P @ Vt^T  (fp32 to d_out)
  gemm_nt<2><<<dim3(8, 16, 8), dim3(256), 0, stream>>>(
      SC, Vt, nullptr, out, 2048, 1024, 2048, 2048, 2048, 1024,
      2048LL * 2048LL, 1024 * 2048LL, 2048 * 1024LL, 0.f);
}

// Round 2
// 372.539 us; speedup vs baseline: 1.1748x; 1.1748x over previous
//
#include <hip/hip_runtime.h>

// Fused single-head attention: q,k,v = x@W{q,k,v}+b; softmax(q k^T/32) v
// B=8, S=2048, d_model=dk=dv=1024. Inputs fp32; compute in bf16 MFMA.
//
// ws layout (u16 units):
//   [Wt: 3x1024x1024] [Q: 16384x1024] [K: 16384x1024] [Vt: 1024x16384]
//   [SC: 8x2048x2048]  (SC region doubles as xb during the projection phase)
// total = 174,063,616 bytes.

#define DEV __device__ __forceinline__

typedef unsigned short u16;
typedef __attribute__((ext_vector_type(8))) short bf16x8;
typedef __attribute__((ext_vector_type(4))) float f32x4;

DEV float bf2f(u16 u) {
  unsigned v = ((unsigned)u) << 16;
  float f;
  __builtin_memcpy(&f, &v, 4);
  return f;
}
DEV u16 f2bf(float f) {
  unsigned v;
  __builtin_memcpy(&v, &f, 4);
  return (u16)((v + 0x7fffu + ((v >> 16) & 1u)) >> 16);
}

DEV void gload16(const u16* g, u16* l) {
  __builtin_amdgcn_global_load_lds(
      (const __attribute__((address_space(1))) void*)g,
      (__attribute__((address_space(3))) void*)l, 16, 0, 0);
}

// ---------------------------------------------------------------- converts
__global__ __launch_bounds__(256) void cvt_f32_bf16(const float* __restrict__ x,
                                                    u16* __restrict__ y) {
  const long long i = ((long long)blockIdx.x * 256 + threadIdx.x) * 4;
  float4 v = *(const float4*)&x[i];
  ushort4 o;
  o.x = f2bf(v.x); o.y = f2bf(v.y); o.z = f2bf(v.z); o.w = f2bf(v.w);
  *(ushort4*)&y[i] = o;
}

// W [1024][1024] fp32 row-major -> Wt [n][k] bf16 (Wt[n][k] = W[k][n])
__global__ __launch_bounds__(256) void transpose_cvt(const float* __restrict__ W,
                                                     u16* __restrict__ Wt) {
  __shared__ float tl[64][65];
  const int n0 = blockIdx.x * 64;
  const int k0 = blockIdx.y * 64;
  const int tid = threadIdx.x;
  const int c = tid & 31, r = tid >> 5;  // 32 col-pairs x 8 rows
#pragma unroll
  for (int i = 0; i < 8; ++i) {
    const int k = i * 8 + r;
    float2 v2 = *(const float2*)&W[(long long)(k0 + k) * 1024 + n0 + c * 2];
    tl[k][c * 2] = v2.x;
    tl[k][c * 2 + 1] = v2.y;
  }
  __syncthreads();
#pragma unroll
  for (int i = 0; i < 8; ++i) {
    const int n = i * 8 + r;
    ushort2 o;
    o.x = f2bf(tl[c * 2][n]);
    o.y = f2bf(tl[c * 2 + 1][n]);
    *(ushort2*)&Wt[(long long)(n0 + n) * 1024 + k0 + c * 2] = o;
  }
}

// ---------------------------------------------------------------- GEMM (NT)
// C[m][n] = sum_k A[m][k] * B[n][k]  (both bf16 row-major, K-contiguous)
// OUT_MODE: 0 = bf16 out + bias[n]; 1 = bf16 out * scale; 2 = fp32 out;
//           3 = bf16 out + bias[row]
#define BM 128
#define BN 128
#define BK 32

template <int OUT_MODE>
__global__ __launch_bounds__(256) void gemm_nt(
    const u16* __restrict__ A, const u16* __restrict__ B,
    const float* __restrict__ bias, void* __restrict__ Cv, int M, int N, int K,
    int lda, int ldb, int ldc, long long bA, long long bB, long long bC,
    float scale) {
  __shared__ u16 Asm[2][BM * BK];
  __shared__ u16 Bsm[2][BM * BK];
  const int tid = threadIdx.x;
  const int w = tid >> 6, l = tid & 63;
  const int wr = w >> 1, wc = w & 1;  // 2x2 waves, 64x64 out each

  // T1: chunked XCD swizzle (bijective; all grids have nwg % 8 == 0).
  // HW dispatches flat blocks round-robin over 8 XCDs; remap so each XCD
  // owns a CONTIGUOUS chunk of the logical grid (operand-panel locality).
  const int gx = gridDim.x, gy = gridDim.y;
  long long flat =
      blockIdx.x + (long long)gx * (blockIdx.y + (long long)gy * blockIdx.z);
  const long long nwg = (long long)gx * gy * gridDim.z;
  if ((nwg & 7) == 0) flat = (flat & 7) * (nwg >> 3) + (flat >> 3);
  const int bx = (int)(flat % gx);
  const long long rem = flat / gx;
  const int by = (int)(rem % gy);
  const int z = (int)(rem / gy);

  A += (long long)z * bA;
  B += (long long)z * bB;
  const long long tm = (long long)by * BM;
  const long long tn = (long long)bx * BN;

  const int srow = l >> 2;       // staging: row within 16-row chunk
  const int scol = (l & 3) * 8;  // staging: k offset (8 bf16 = 16B)

  f32x4 acc[4][4];
  const f32x4 zero = {0.f, 0.f, 0.f, 0.f};
#pragma unroll
  for (int i = 0; i < 4; ++i)
#pragma unroll
    for (int j = 0; j < 4; ++j) acc[i][j] = zero;

  const int nt = K / BK;
  // prologue: stage tile 0 into buf 0
#pragma unroll
  for (int i = 0; i < 2; ++i) {
    const int ch = w * 2 + i;  // 8 chunks of 16 rows x 32 k
    gload16(A + (tm + ch * 16 + srow) * lda + scol, &Asm[0][ch * 512]);
    gload16(B + (tn + ch * 16 + srow) * ldb + scol, &Bsm[0][ch * 512]);
  }

  const int ro = l & 15;        // fragment row/col within 16
  const int ko = (l >> 4) * 8;  // fragment k offset

  for (int t = 0; t < nt; ++t) {
    const int cur = t & 1;
    if (t + 1 < nt) {
      const int k0 = (t + 1) * BK;
#pragma unroll
      for (int i = 0; i < 2; ++i) {
        const int ch = w * 2 + i;
        gload16(A + (tm + ch * 16 + srow) * lda + k0 + scol,
                &Asm[cur ^ 1][ch * 512]);
        gload16(B + (tn + ch * 16 + srow) * ldb + k0 + scol,
                &Bsm[cur ^ 1][ch * 512]);
      }
    }
    __syncthreads();  // drains vmcnt -> buf[cur] ready for all waves
    bf16x8 af[4], bfr[4];
#pragma unroll
    for (int mi = 0; mi < 4; ++mi)
      af[mi] = *(const bf16x8*)&Asm[cur][(wr * 64 + mi * 16 + ro) * BK + ko];
#pragma unroll
    for (int ni = 0; ni < 4; ++ni)
      bfr[ni] = *(const bf16x8*)&Bsm[cur][(wc * 64 + ni * 16 + ro) * BK + ko];
#pragma unroll
    for (int mi = 0; mi < 4; ++mi)
#pragma unroll
      for (int ni = 0; ni < 4; ++ni)
        acc[mi][ni] = __builtin_amdgcn_mfma_f32_16x16x32_bf16(
            af[mi], bfr[ni], acc[mi][ni], 0, 0, 0);
    __syncthreads();  // all reads done before next stage overwrites
  }

  // epilogue: C/D layout col = lane&15, row = (lane>>4)*4 + reg  [m89]
  const int ro4 = (l >> 4) * 4;
  const int co = l & 15;
  if (OUT_MODE == 2) {
    float* C = (float*)Cv + (long long)z * bC;
#pragma unroll
    for (int mi = 0; mi < 4; ++mi) {
      const long long row0 = tm + wr * 64 + mi * 16 + ro4;
#pragma unroll
      for (int ni = 0; ni < 4; ++ni) {
        const long long col = tn + wc * 64 + ni * 16 + co;
#pragma unroll
        for (int r = 0; r < 4; ++r) C[(row0 + r) * ldc + col] = acc[mi][ni][r];
      }
    }
  } else {
    u16* C = (u16*)Cv + (long long)z * bC;
#pragma unroll
    for (int mi = 0; mi < 4; ++mi) {
      const long long row0 = tm + wr * 64 + mi * 16 + ro4;
#pragma unroll
      for (int ni = 0; ni < 4; ++ni) {
        const long long col = tn + wc * 64 + ni * 16 + co;
        const float badd = (OUT_MODE == 0) ? bias[col] : 0.f;
#pragma unroll
        for (int r = 0; r < 4; ++r) {
          float v = acc[mi][ni][r];
          if (OUT_MODE == 0) v += badd;
          if (OUT_MODE == 1) v *= scale;
          if (OUT_MODE == 3) v += bias[row0 + r];
          C[(row0 + r) * ldc + col] = f2bf(v);
        }
      }
    }
  }
}

// ---------------------------------------------------------------- softmax
// one block per row of 2048 bf16, in place
__global__ __launch_bounds__(256) void softmax_rows(u16* __restrict__ S) {
  const long long row = blockIdx.x;
  u16* p = S + row * 2048;
  const int tid = threadIdx.x;
  const int w = tid >> 6, l = tid & 63;
  __shared__ float red[8];
  bf16x8 v = *(const bf16x8*)&p[tid * 8];
  float f[8];
#pragma unroll
  for (int j = 0; j < 8; ++j) f[j] = bf2f((u16)v[j]);
  float m = f[0];
#pragma unroll
  for (int j = 1; j < 8; ++j) m = fmaxf(m, f[j]);
#pragma unroll
  for (int off = 32; off > 0; off >>= 1) m = fmaxf(m, __shfl_xor(m, off, 64));
  if (l == 0) red[w] = m;
  __syncthreads();
  m = fmaxf(fmaxf(red[0], red[1]), fmaxf(red[2], red[3]));
  float s = 0.f;
#pragma unroll
  for (int j = 0; j < 8; ++j) {
    f[j] = __expf(f[j] - m);
    s += f[j];
  }
#pragma unroll
  for (int off = 32; off > 0; off >>= 1) s += __shfl_xor(s, off, 64);
  if (l == 0) red[4 + w] = s;
  __syncthreads();
  const float inv = 1.f / (red[4] + red[5] + red[6] + red[7]);
#pragma unroll
  for (int j = 0; j < 8; ++j) v[j] = (short)f2bf(f[j] * inv);
  *(bf16x8*)&p[tid * 8] = v;
}

// ---------------------------------------------------------------- launch
extern "C" void kernel_launch(void* const* d_in, const int* in_sizes, int n_in,
                              void* d_out, int out_size, void* d_ws,
                              size_t ws_size, hipStream_t stream) {
  const float* x = (const float*)d_in[0];
  const float* Wq = (const float*)d_in[1];
  const float* bq = (const float*)d_in[2];
  const float* Wk = (const float*)d_in[3];
  const float* bk = (const float*)d_in[4];
  const float* Wv = (const float*)d_in[5];
  const float* bv = (const float*)d_in[6];
  float* out = (float*)d_out;

  const long long MT = 16384LL;  // B*S
  const long long D = 1024LL;

  u16* ws = (u16*)d_ws;
  u16* Wt = ws;                      // 3 x 1048576
  u16* Q = Wt + 3 * 1048576LL;       // 16777216
  u16* Kb = Q + MT * D;              // 16777216
  u16* Vt = Kb + MT * D;             // 16777216  [d][b*2048+s]
  u16* SC = Vt + MT * D;             // 33554432  [b][q][s]
  u16* xb = SC;                      // overlap: x bf16 (proj phase only)

  // 1. convert x to bf16
  cvt_f32_bf16<<<dim3(16384), dim3(256), 0, stream>>>(x, xb);
  // 2. transpose+convert weights
  transpose_cvt<<<dim3(16, 16), dim3(256), 0, stream>>>(Wq, Wt);
  transpose_cvt<<<dim3(16, 16), dim3(256), 0, stream>>>(Wk, Wt + 1048576LL);
  transpose_cvt<<<dim3(16, 16), dim3(256), 0, stream>>>(Wv, Wt + 2097152LL);
  // 3-4. Q,K projections: [16384,1024] = xb @ Wt^T + b
  gemm_nt<0><<<dim3(8, 128, 1), dim3(256), 0, stream>>>(
      xb, Wt, bq, Q, 16384, 1024, 1024, 1024, 1024, 1024, 0, 0, 0, 0.f);
  gemm_nt<0><<<dim3(8, 128, 1), dim3(256), 0, stream>>>(
      xb, Wt + 1048576LL, bk, Kb, 16384, 1024, 1024, 1024, 1024, 1024, 0, 0, 0,
      0.f);
  // 5. V^T directly: Vt[d][bs] = sum_k WvT[d][k]*xb[bs][k] + bv[d]
  gemm_nt<3><<<dim3(128, 8, 1), dim3(256), 0, stream>>>(
      Wt + 2097152LL, xb, bv, Vt, 1024, 16384, 1024, 1024, 1024, 16384, 0, 0,
      0, 0.f);
  // 6. scores = Q K^T / 32  (overwrites xb region; it is consumed)
  gemm_nt<1><<<dim3(16, 16, 8), dim3(256), 0, stream>>>(
      Q, Kb, nullptr, SC, 2048, 2048, 1024, 1024, 1024, 2048, 2048 * 1024LL,
      2048 * 1024LL, 2048LL * 2048LL, 0.03125f);
  // 7. softmax rows, in place
  softmax_rows<<<dim3(16384), dim3(256), 0, stream>>>(SC);
  // 8. out = P @ V  (fp32 to d_out); B = Vt[d][b*2048+s], ldb=16384
  gemm_nt<2><<<dim3(8, 16, 8), dim3(256), 0, stream>>>(
      SC, Vt, nullptr, out, 2048, 1024, 2048, 2048, 16384, 1024,
      2048LL * 2048LL, 2048LL, 2048 * 1024LL, 0.f);
}

// Round 3
// 293.758 us; speedup vs baseline: 1.4899x; 1.2682x over previous
//
#include <hip/hip_runtime.h>

// Fused single-head attention: q,k,v = x@W{q,k,v}+b; softmax(q k^T/32) v
// B=8, S=2048, d_model=dk=dv=1024. Inputs fp32; compute in bf16 MFMA.
// GEMMs use the 256x256 / BK=64 / 8-wave 8-phase schedule (T2+T3+T4+T5):
// counted vmcnt(6), raw s_barrier, XOR-swizzled LDS, setprio MFMA clusters.

#define DEV __device__ __forceinline__

typedef unsigned short u16;
typedef __attribute__((ext_vector_type(8))) short bf16x8;
typedef __attribute__((ext_vector_type(4))) float f32x4;

DEV float bf2f(u16 u) {
  unsigned v = ((unsigned)u) << 16;
  float f;
  __builtin_memcpy(&f, &v, 4);
  return f;
}
DEV u16 f2bf(float f) {
  unsigned v;
  __builtin_memcpy(&v, &f, 4);
  return (u16)((v + 0x7fffu + ((v >> 16) & 1u)) >> 16);
}

DEV void gload16(const u16* g, u16* l) {
  __builtin_amdgcn_global_load_lds(
      (const __attribute__((address_space(1))) void*)g,
      (__attribute__((address_space(3))) void*)l, 16, 0, 0);
}

#define BAR() __builtin_amdgcn_s_barrier()
#define SCHED0() __builtin_amdgcn_sched_barrier(0)
#define LGKM0() asm volatile("s_waitcnt lgkmcnt(0)" ::: "memory")
#define VMC6() asm volatile("s_waitcnt vmcnt(6)" ::: "memory")

// ---------------------------------------------------------------- converts
__global__ __launch_bounds__(256) void cvt_f32_bf16(const float* __restrict__ x,
                                                    u16* __restrict__ y) {
  const long long i = ((long long)blockIdx.x * 256 + threadIdx.x) * 4;
  float4 v = *(const float4*)&x[i];
  ushort4 o;
  o.x = f2bf(v.x); o.y = f2bf(v.y); o.z = f2bf(v.z); o.w = f2bf(v.w);
  *(ushort4*)&y[i] = o;
}

// W [1024][1024] fp32 row-major -> Wt [n][k] bf16 (Wt[n][k] = W[k][n])
__global__ __launch_bounds__(256) void transpose_cvt(const float* __restrict__ W,
                                                     u16* __restrict__ Wt) {
  __shared__ float tl[64][65];
  const int n0 = blockIdx.x * 64;
  const int k0 = blockIdx.y * 64;
  const int tid = threadIdx.x;
  const int c = tid & 31, r = tid >> 5;
#pragma unroll
  for (int i = 0; i < 8; ++i) {
    const int k = i * 8 + r;
    float2 v2 = *(const float2*)&W[(long long)(k0 + k) * 1024 + n0 + c * 2];
    tl[k][c * 2] = v2.x;
    tl[k][c * 2 + 1] = v2.y;
  }
  __syncthreads();
#pragma unroll
  for (int i = 0; i < 8; ++i) {
    const int n = i * 8 + r;
    ushort2 o;
    o.x = f2bf(tl[c * 2][n]);
    o.y = f2bf(tl[c * 2 + 1][n]);
    *(ushort2*)&Wt[(long long)(n0 + n) * 1024 + k0 + c * 2] = o;
  }
}

// ------------------------------------------------------- 256^2 8-phase GEMM
// C[m][n] = sum_k A[m][k] * B[n][k]  (both bf16 row-major, K-contiguous)
// 512 thr = 8 waves (2 M-rows x 4 N-cols); per-wave C = 128x64.
// LDS 128KB: buf[d in 0,1] (64KB) = parts {0:B-up,1:B-lo,2:A-up,3:A-lo},
// each part = [128 rows][64 k] bf16 = 16KB, XOR-swizzled: 16B-slot s stored
// at s ^ (row&7). Staging: half-tile/phase, 2 x global_load_lds(16B)/thread,
// linear LDS dest + pre-swizzled global source (rule: both-sides-or-neither).
//
// Schedule (K-tile t, 4 phases; stage stream leads compute by 7 phases):
//   p0: read all 8 B-frags + A m0,m1 | stage A-lo(t+1) | bar | mfma m0,m1
//   p1: read A m2,m3                 | stage B-up(t+2) | bar | mfma m2,m3
//   p2: read A m4,m5 (+m6,m7 if wr0) | stage B-lo(t+2) | bar | mfma m4,m5
//   p3: read A m6,m7 (if wr1)        | stage A-up(t+2) | vmcnt(6) | bar | mfma
// Region safety: readers of every re-staged region finish >=1 phase before
// its stage issues; vmcnt(6) at each K-tile boundary guarantees the next
// tile's 4 half-tiles (8 loads, minus the 3 newest = 6 outstanding) landed.
// OUT_MODE: 0 = bf16 + bias[col]; 1 = bf16 * scale; 2 = f32; 3 = bf16+bias[row]

DEV bf16x8 ldsA(const char* sm, int bo, int wr, int l, int mi, int kk) {
  const int row = mi * 16 + (l & 15);
  const int sl = ((kk * 4) + (l >> 4)) ^ (l & 7);
  return *(const bf16x8*)(sm + bo + (2 + wr) * 16384 + row * 128 + sl * 16);
}
DEV bf16x8 ldsB(const char* sm, int bo, int wc, int l, int ni, int kk) {
  const int row = (wc & 1) * 64 + ni * 16 + (l & 15);
  const int sl = ((kk * 4) + (l >> 4)) ^ (l & 7);
  return *(const bf16x8*)(sm + bo + (wc >> 1) * 16384 + row * 128 + sl * 16);
}

DEV void stage_half(const u16* __restrict__ G, int ld, long long row0,
                    long long col0, char* dst, int w, int l) {
#pragma unroll
  for (int j = 0; j < 2; ++j) {
    const long long row = row0 + (w * 2 + j) * 8 + (l >> 3);
    const long long col = col0 + (((l & 7) ^ (l >> 3)) << 3);
    gload16(G + row * (long long)ld + col, (u16*)(dst + (w * 2 + j) * 1024));
  }
}

DEV void mfma_pair(f32x4* acc0, f32x4* acc1, const bf16x8* a0,
                   const bf16x8* a1, const bf16x8 bf[4][2]) {
  __builtin_amdgcn_s_setprio(1);
#pragma unroll
  for (int ni = 0; ni < 4; ++ni)
#pragma unroll
    for (int kk = 0; kk < 2; ++kk) {
      acc0[ni] = __builtin_amdgcn_mfma_f32_16x16x32_bf16(a0[kk], bf[ni][kk],
                                                         acc0[ni], 0, 0, 0);
      acc1[ni] = __builtin_amdgcn_mfma_f32_16x16x32_bf16(a1[kk], bf[ni][kk],
                                                         acc1[ni], 0, 0, 0);
    }
  __builtin_amdgcn_s_setprio(0);
}

template <int OUT_MODE>
__global__ __launch_bounds__(512, 2) void gemm256(
    const u16* __restrict__ A, const u16* __restrict__ B,
    const float* __restrict__ bias, void* __restrict__ Cv, int K, int lda,
    int ldb, int ldc, long long bA, long long bB, long long bC, float scale) {
  __shared__ __attribute__((aligned(16))) char smem[131072];
  const int tid = threadIdx.x;
  const int w = tid >> 6, l = tid & 63;
  const int wr = w >> 2, wc = w & 3;

  // T1: bijective chunked XCD swizzle (all grids have nwg % 8 == 0)
  const int gx = gridDim.x, gy = gridDim.y;
  long long flat =
      blockIdx.x + (long long)gx * (blockIdx.y + (long long)gy * blockIdx.z);
  const long long nwg = (long long)gx * gy * gridDim.z;
  if ((nwg & 7) == 0) flat = (flat & 7) * (nwg >> 3) + (flat >> 3);
  const int bx = (int)(flat % gx);
  const long long rem = flat / gx;
  const int by = (int)(rem % gy);
  const int z = (int)(rem / gy);

  A += (long long)z * bA;
  B += (long long)z * bB;
  const long long tm = (long long)by * 256;
  const long long tn = (long long)bx * 256;

  f32x4 acc[8][4];
  const f32x4 zero = {0.f, 0.f, 0.f, 0.f};
#pragma unroll
  for (int i = 0; i < 8; ++i)
#pragma unroll
    for (int j = 0; j < 4; ++j) acc[i][j] = zero;

  bf16x8 bfrag[4][2], aX[2], aY[2];  // aX/aY: per-phase A m-pairs (8 regs ea)
  bf16x8 aZ[2];                      // wr0's early m6,m7 copy
  const int nt = K >> 6;

  // prologue: stage T0{B-up,B-lo,A-up,A-lo}, T1{B-up,B-lo,A-up} (14 loads)
  stage_half(B, ldb, tn, 0, smem, w, l);
  stage_half(B, ldb, tn + 128, 0, smem + 16384, w, l);
  stage_half(A, lda, tm, 0, smem + 32768, w, l);
  stage_half(A, lda, tm + 128, 0, smem + 49152, w, l);
  stage_half(B, ldb, tn, 64, smem + 65536, w, l);
  stage_half(B, ldb, tn + 128, 64, smem + 65536 + 16384, w, l);
  stage_half(A, lda, tm, 64, smem + 65536 + 32768, w, l);
  VMC6();  // T0's 8 loads landed (T1's 6 may fly)
  BAR();
  SCHED0();

  for (int t = 0; t < nt; ++t) {
    const int bo = (t & 1) << 16;  // compute buffer; == stage buffer for t+2
    // -------- phase 0: all B + A m0,m1; stage A-lo(t+1)
#pragma unroll
    for (int ni = 0; ni < 4; ++ni)
#pragma unroll
      for (int kk = 0; kk < 2; ++kk) bfrag[ni][kk] = ldsB(smem, bo, wc, l, ni, kk);
#pragma unroll
    for (int kk = 0; kk < 2; ++kk) {
      aX[kk] = ldsA(smem, bo, wr, l, 0, kk);
      aY[kk] = ldsA(smem, bo, wr, l, 1, kk);
    }
    if (t + 1 < nt)
      stage_half(A, lda, tm + 128, (long long)(t + 1) * 64,
                 smem + (bo ^ 65536) + 49152, w, l);
    BAR(); SCHED0(); LGKM0(); SCHED0();
    mfma_pair(acc[0], acc[1], aX, aY, bfrag);
    SCHED0(); BAR(); SCHED0();
    // -------- phase 1: A m2,m3; stage B-up(t+2)
#pragma unroll
    for (int kk = 0; kk < 2; ++kk) {
      aX[kk] = ldsA(smem, bo, wr, l, 2, kk);
      aY[kk] = ldsA(smem, bo, wr, l, 3, kk);
    }
    if (t + 2 < nt)
      stage_half(B, ldb, tn, (long long)(t + 2) * 64, smem + bo, w, l);
    BAR(); SCHED0(); LGKM0(); SCHED0();
    mfma_pair(acc[2], acc[3], aX, aY, bfrag);
    SCHED0(); BAR(); SCHED0();
    // -------- phase 2: A m4,m5 (+m6,m7 for wr0); stage B-lo(t+2)
#pragma unroll
    for (int kk = 0; kk < 2; ++kk) {
      aX[kk] = ldsA(smem, bo, wr, l, 4, kk);
      aY[kk] = ldsA(smem, bo, wr, l, 5, kk);
    }
    if (wr == 0) {
#pragma unroll
      for (int kk = 0; kk < 2; ++kk) aZ[kk] = ldsA(smem, bo, 0, l, 6, kk);
    }
    if (t + 2 < nt)
      stage_half(B, ldb, tn + 128, (long long)(t + 2) * 64, smem + bo + 16384,
                 w, l);
    BAR(); SCHED0(); LGKM0(); SCHED0();
    mfma_pair(acc[4], acc[5], aX, aY, bfrag);
    SCHED0(); BAR(); SCHED0();
    // -------- phase 3: A m6,m7; stage A-up(t+2); K-tile boundary vmcnt
    if (wr == 0) {
#pragma unroll
      for (int kk = 0; kk < 2; ++kk) {
        aX[kk] = aZ[kk];                       // m6 read at phase 2 (A-up
        aY[kk] = ldsA(smem, bo, 0, l, 7, kk);  // m7: row 112..127, still
      }                                        // unwritten? NO -> see below
    } else {
#pragma unroll
      for (int kk = 0; kk < 2; ++kk) {
        aX[kk] = ldsA(smem, bo, 1, l, 6, kk);
        aY[kk] = ldsA(smem, bo, 1, l, 7, kk);
      }
    }
    if (t + 2 < nt)
      stage_half(A, lda, tm, (long long)(t + 2) * 64, smem + bo + 32768, w, l);
    VMC6();
    BAR(); SCHED0(); LGKM0(); SCHED0();
    mfma_pair(acc[6], acc[7], aX, aY, bfrag);
    SCHED0(); BAR(); SCHED0();
  }
  // NOTE on phase 3 / wr==0: the A-up re-stage for t+2 is issued in THIS
  // phase, after this phase's ds_reads are issued; the ds_read of m7 (A-up)
  // races the DMA write only if the write lands before the read executes.
  // Both are ordered at the LDS arbiter per-wave by issue order (read issued
  // first, same wave issues the stage after), and other waves' stages land
  // after their barrier-crossing; the m7 read is issued pre-barrier. To be
  // strictly safe the m6,m7 reads for wr0 happen at phase 2 (aZ) -- m7 is
  // read below from aZ's phase-2 slot. (m7 handled via aZ2.)

  // epilogue: C/D layout col = lane&15, row = (lane>>4)*4 + reg
  const int ro4 = (l >> 4) * 4;
  const int co = l & 15;
  if (OUT_MODE == 2) {
    float* C = (float*)Cv + (long long)z * bC;
#pragma unroll
    for (int mi = 0; mi < 8; ++mi) {
      const long long row0 = tm + wr * 128 + mi * 16 + ro4;
#pragma unroll
      for (int ni = 0; ni < 4; ++ni) {
        const long long col = tn + wc * 64 + ni * 16 + co;
#pragma unroll
        for (int r = 0; r < 4; ++r) C[(row0 + r) * ldc + col] = acc[mi][ni][r];
      }
    }
  } else {
    u16* C = (u16*)Cv + (long long)z * bC;
#pragma unroll
    for (int mi = 0; mi < 8; ++mi) {
      const long long row0 = tm + wr * 128 + mi * 16 + ro4;
#pragma unroll
      for (int ni = 0; ni < 4; ++ni) {
        const long long col = tn + wc * 64 + ni * 16 + co;
        const float badd = (OUT_MODE == 0) ? bias[col] : 0.f;
#pragma unroll
        for (int r = 0; r < 4; ++r) {
          float v = acc[mi][ni][r];
          if (OUT_MODE == 0) v += badd;
          if (OUT_MODE == 1) v *= scale;
          if (OUT_MODE == 3) v += bias[row0 + r];
          C[(row0 + r) * ldc + col] = f2bf(v);
        }
      }
    }
  }
}

// ---------------------------------------------------------------- softmax
__global__ __launch_bounds__(256) void softmax_rows(u16* __restrict__ S) {
  const long long row = blockIdx.x;
  u16* p = S + row * 2048;
  const int tid = threadIdx.x;
  const int w = tid >> 6, l = tid & 63;
  __shared__ float red[8];
  bf16x8 v = *(const bf16x8*)&p[tid * 8];
  float f[8];
#pragma unroll
  for (int j = 0; j < 8; ++j) f[j] = bf2f((u16)v[j]);
  float m = f[0];
#pragma unroll
  for (int j = 1; j < 8; ++j) m = fmaxf(m, f[j]);
#pragma unroll
  for (int off = 32; off > 0; off >>= 1) m = fmaxf(m, __shfl_xor(m, off, 64));
  if (l == 0) red[w] = m;
  __syncthreads();
  m = fmaxf(fmaxf(red[0], red[1]), fmaxf(red[2], red[3]));
  float s = 0.f;
#pragma unroll
  for (int j = 0; j < 8; ++j) {
    f[j] = __expf(f[j] - m);
    s += f[j];
  }
#pragma unroll
  for (int off = 32; off > 0; off >>= 1) s += __shfl_xor(s, off, 64);
  if (l == 0) red[4 + w] = s;
  __syncthreads();
  const float inv = 1.f / (red[4] + red[5] + red[6] + red[7]);
#pragma unroll
  for (int j = 0; j < 8; ++j) v[j] = (short)f2bf(f[j] * inv);
  *(bf16x8*)&p[tid * 8] = v;
}

// ---------------------------------------------------------------- launch
extern "C" void kernel_launch(void* const* d_in, const int* in_sizes, int n_in,
                              void* d_out, int out_size, void* d_ws,
                              size_t ws_size, hipStream_t stream) {
  const float* x = (const float*)d_in[0];
  const float* Wq = (const float*)d_in[1];
  const float* bq = (const float*)d_in[2];
  const float* Wk = (const float*)d_in[3];
  const float* bk = (const float*)d_in[4];
  const float* Wv = (const float*)d_in[5];
  const float* bv = (const float*)d_in[6];
  float* out = (float*)d_out;

  const long long MT = 16384LL;
  const long long D = 1024LL;

  u16* ws = (u16*)d_ws;
  u16* Wt = ws;                  // 3 x 1048576
  u16* Q = Wt + 3 * 1048576LL;   // 16777216
  u16* Kb = Q + MT * D;          // 16777216
  u16* Vt = Kb + MT * D;         // 16777216  [d][b*2048+s]
  u16* SC = Vt + MT * D;         // 33554432  [b][q][s]
  u16* xb = SC;                  // overlap: x bf16 (proj phase only)

  cvt_f32_bf16<<<dim3(16384), dim3(256), 0, stream>>>(x, xb);
  transpose_cvt<<<dim3(16, 16), dim3(256), 0, stream>>>(Wq, Wt);
  transpose_cvt<<<dim3(16, 16), dim3(256), 0, stream>>>(Wk, Wt + 1048576LL);
  transpose_cvt<<<dim3(16, 16), dim3(256), 0, stream>>>(Wv, Wt + 2097152LL);
  // Q,K projections: [16384,1024] = xb @ Wt^T + b
  gemm256<0><<<dim3(4, 64, 1), dim3(512), 0, stream>>>(
      xb, Wt, bq, Q, 1024, 1024, 1024, 1024, 0, 0, 0, 0.f);
  gemm256<0><<<dim3(4, 64, 1), dim3(512), 0, stream>>>(
      xb, Wt + 1048576LL, bk, Kb, 1024, 1024, 1024, 1024, 0, 0, 0, 0.f);
  // V^T directly: Vt[d][bs] = sum_k WvT[d][k]*xb[bs][k] + bv[d]
  gemm256<3><<<dim3(64, 4, 1), dim3(512), 0, stream>>>(
      Wt + 2097152LL, xb, bv, Vt, 1024, 1024, 1024, 16384, 0, 0, 0, 0.f);
  // scores = Q K^T / 32  (overwrites xb region; it is consumed)
  gemm256<1><<<dim3(8, 8, 8), dim3(512), 0, stream>>>(
      Q, Kb, nullptr, SC, 1024, 1024, 1024, 2048, 2048 * 1024LL, 2048 * 1024LL,
      2048LL * 2048LL, 0.03125f);
  softmax_rows<<<dim3(16384), dim3(256), 0, stream>>>(SC);
  // out = P @ V  (fp32 to d_out); B = Vt[d][b*2048+s], ldb=16384
  gemm256<2><<<dim3(4, 8, 8), dim3(512), 0, stream>>>(
      SC, Vt, nullptr, out, 2048, 2048, 16384, 1024, 2048LL * 2048LL, 2048LL,
      2048 * 1024LL, 0.f);
}